// Round 3
// baseline (364.115 us; speedup 1.0000x reference)
//
#include <hip/hip_runtime.h>

typedef __attribute__((ext_vector_type(4))) float f32x4;
typedef __attribute__((ext_vector_type(8))) __bf16 bf16x8;
typedef __attribute__((ext_vector_type(8))) unsigned short ushort8;

static __device__ __forceinline__ unsigned short f2bf(float f) {
  unsigned u = __float_as_uint(f);
  u += 0x7fffu + ((u >> 16) & 1u);   // RNE
  return (unsigned short)(u >> 16);
}
static __device__ __forceinline__ float bf2f(unsigned short s) {
  return __uint_as_float(((unsigned)s) << 16);
}

// ---------------------------------------------------------------------------
// Kernel 1: LDS-tiled transpose x[b][ci][p] (f32) -> xT[b][p][ci] (bf16),
// plus weight repack conv_w[co][ci][3][3] -> wpk[tap][co][ci] (bf16).
// ---------------------------------------------------------------------------
__global__ __launch_bounds__(256, 1) void k_xpose(
    const float* __restrict__ x, const float* __restrict__ cw,
    unsigned short* __restrict__ xT, unsigned short* __restrict__ wpk) {
  int bid = blockIdx.x;
  int t = threadIdx.x;
  if (bid < 896) {
    __shared__ float xl[64 * 57];            // [ci 64][p 56 pad 57]
    int pt = bid % 14, cit = (bid / 14) & 7, b = bid / 112;
    int p0 = pt * 56, ci0 = cit * 64;
#pragma unroll
    for (int i = 0; i < 4; ++i) {            // 896 f32x4 coalesced reads
      int idx = i * 256 + t;
      if (idx < 896) {
        int ci = idx / 14, p4 = (idx % 14) * 4;
        f32x4 v = *reinterpret_cast<const f32x4*>(
            x + ((size_t)(b * 512 + ci0 + ci)) * 784 + p0 + p4);
        *reinterpret_cast<f32x4*>(&xl[ci * 57 + p4]) = v;
      }
    }
    __syncthreads();
#pragma unroll
    for (int i = 0; i < 2; ++i) {            // 448 ushort8 coalesced writes
      int idx = i * 256 + t;
      if (idx < 448) {
        int p = idx >> 3, c8 = (idx & 7) * 8;
        ushort8 o;
#pragma unroll
        for (int j = 0; j < 8; ++j) o[j] = f2bf(xl[(c8 + j) * 57 + p]);
        *reinterpret_cast<ushort8*>(
            xT + ((size_t)(b * 784 + p0 + p)) * 512 + ci0 + c8) = o;
      }
    }
  } else {                                   // 72 blocks * 4096 = 294912 wpk elems
    int o0 = (bid - 896) * 4096 + t * 16;
    ushort8 w0, w1;
#pragma unroll
    for (int j = 0; j < 16; ++j) {
      int o = o0 + j;
      int ci = o & 511, co = (o >> 9) & 63, tap = o >> 15;
      unsigned short v = f2bf(cw[((size_t)(co * 512 + ci)) * 9 + tap]);
      if (j < 8) w0[j] = v; else w1[j - 8] = v;
    }
    *reinterpret_cast<ushort8*>(wpk + o0) = w0;
    *reinterpret_cast<ushort8*>(wpk + o0 + 8) = w1;
  }
}

// ---------------------------------------------------------------------------
// Kernel 2: conv3x3 via bf16 MFMA, tap-decomposed implicit GEMM.
// grid 448 = 8b * 7px * 2co2 * 4split ; block 128 (2 waves)
// bias folded into the s==0 accumulator init. writes am_part[s][b][p][co]
// ---------------------------------------------------------------------------
#define CPAD 56
__global__ __launch_bounds__(128, 1) void k_conv(
    const unsigned short* __restrict__ xT, const unsigned short* __restrict__ wpk,
    const float* __restrict__ cb, float* __restrict__ am_part) {
  __shared__ unsigned short wl[9 * 32 * CPAD];  // [tap][co_l 32][ci 32 pad 56]
  __shared__ unsigned short xl[168 * CPAD];     // [pos 6rows*28][ci 32 pad 56]
  int bid = blockIdx.x;
  int s  = bid & 3;
  int c2 = (bid >> 2) & 1;
  int px = (bid >> 3) % 7;
  int b  = bid / 56;
  int t = threadIdx.x;
  int W = t >> 6, lane = t & 63;
  int co_base = c2 * 32;
  int p0 = px * 112, h0 = px * 4;
  int n = lane & 15, kg = lane >> 4;

  int lrow0[7], wc[7];
#pragma unroll
  for (int f = 0; f < 7; ++f) {
    int pit = f * 16 + n;
    lrow0[f] = pit / 28 + 1;
    wc[f]    = pit % 28;
  }
  f32x4 acc[7];
  f32x4 cb4 = {0.f, 0.f, 0.f, 0.f};
  if (s == 0)
    cb4 = *reinterpret_cast<const f32x4*>(cb + co_base + W * 16 + kg * 4);
#pragma unroll
  for (int f = 0; f < 7; ++f) acc[f] = cb4;
  const ushort8 bzero = {0, 0, 0, 0, 0, 0, 0, 0};

  for (int c = 0; c < 4; ++c) {           // 4 ci-chunks of 32 (split covers 128 ci)
    int ci_c = s * 128 + c * 32;
    __syncthreads();
#pragma unroll
    for (int i = 0; i < 9; ++i) {         // stage weights
      int q = i * 128 + t;
      int tapco = q >> 2, ci8 = (q & 3) * 8;
      int tap = tapco >> 5, co_l = tapco & 31;
      ushort8 v = *reinterpret_cast<const ushort8*>(
          wpk + ((size_t)(tap * 64 + co_base + co_l)) * 512 + ci_c + ci8);
      *reinterpret_cast<ushort8*>(&wl[(tap * 32 + co_l) * CPAD + ci8]) = v;
    }
#pragma unroll
    for (int i = 0; i < 6; ++i) {         // stage x halo tile
      int q = i * 128 + t;
      if (q < 672) {
        int pos = q >> 2, ci8 = (q & 3) * 8;
        int lr = pos / 28, c_ = pos % 28;
        int h = h0 - 1 + lr;
        ushort8 v = bzero;
        if (h >= 0 && h < 28)
          v = *reinterpret_cast<const ushort8*>(
              xT + ((size_t)(b * 784 + h * 28 + c_)) * 512 + ci_c + ci8);
        *reinterpret_cast<ushort8*>(&xl[pos * CPAD + ci8]) = v;
      }
    }
    __syncthreads();
#pragma unroll
    for (int tap = 0; tap < 9; ++tap) {
      int dh = tap / 3 - 1, dw = tap % 3 - 1;
      bf16x8 a = *reinterpret_cast<const bf16x8*>(
          &wl[(tap * 32 + W * 16 + n) * CPAD + kg * 8]);
#pragma unroll
      for (int f = 0; f < 7; ++f) {
        int wcd = wc[f] + dw;
        bool valid = (unsigned)wcd < 28u;
        int pos = (lrow0[f] + dh) * 28 + wcd;
        int posc = valid ? pos : 0;
        ushort8 bv = *reinterpret_cast<const ushort8*>(&xl[posc * CPAD + kg * 8]);
        if (!valid) bv = bzero;
        acc[f] = __builtin_amdgcn_mfma_f32_16x16x32_bf16(
            a, __builtin_bit_cast(bf16x8, bv), acc[f], 0, 0, 0);
      }
    }
  }
#pragma unroll
  for (int f = 0; f < 7; ++f) {
    int p  = p0 + f * 16 + n;
    int co = co_base + W * 16 + kg * 4;
    *reinterpret_cast<f32x4*>(
        am_part + ((size_t)((s * 8 + b) * 784 + p)) * 64 + co) = acc[f];
  }
}

// ---------------------------------------------------------------------------
// Kernel 3: outer-product partial max-pool, v3.
// grid 224 = 8b * 4cit * 7pc ; block 256. Tile: 128ci x 64co x 112p.
// x from xT (bf16), am summed from 4 splits at staging time.
// Threads split p into 2x56 (t>>7), 8ci x 8co per thread, p-paired max3.
// writes pmax[pcc 14][b][ci][co]
// ---------------------------------------------------------------------------
#define XPAD 144   // shorts per p-row (288 B, bank-stride 8 -> 2-way max)
#define APAD 72    // floats per p-row (288 B)
__global__ __launch_bounds__(256, 1) void k_pool(
    const unsigned short* __restrict__ xT, const float* __restrict__ am_part,
    float* __restrict__ pmax) {
  __shared__ unsigned short xls[112 * XPAD]; // 32256 B  [p][ci 128]
  __shared__ float aml[112 * APAD];          // 32256 B  [p][co 64]
  int bid = blockIdx.x;
  int pc  = bid % 7;
  int cit = (bid / 7) & 3;
  int b   = bid / 28;
  int t = threadIdx.x;
  int p0 = pc * 112, ci0 = cit * 128;
#pragma unroll
  for (int i = 0; i < 7; ++i) {      // stage xT tile: 1792 ushort8
    int idx = i * 256 + t;
    int p = idx >> 4, c8 = (idx & 15) * 8;
    ushort8 v = *reinterpret_cast<const ushort8*>(
        xT + ((size_t)(b * 784 + p0 + p)) * 512 + ci0 + c8);
    *reinterpret_cast<ushort8*>(&xls[p * XPAD + c8]) = v;
  }
#pragma unroll
  for (int i = 0; i < 7; ++i) {      // stage am tile: 1792 f32x4, sum 4 splits
    int idx = i * 256 + t;
    int p = idx >> 4, co4 = (idx & 15) * 4;
    size_t o0 = ((size_t)(b * 784 + p0 + p)) * 64 + co4;
    f32x4 v = *reinterpret_cast<const f32x4*>(am_part + o0);
#pragma unroll
    for (int s2 = 1; s2 < 4; ++s2)
      v = v + *reinterpret_cast<const f32x4*>(am_part + o0 + (size_t)s2 * 8 * 784 * 64);
    *reinterpret_cast<f32x4*>(&aml[p * APAD + co4]) = v;
  }
  __syncthreads();
  int half = t >> 7;                 // p-half: 0 -> p 0..55, 1 -> p 56..111
  int t1 = t & 127;
  int ci8 = (t1 >> 3) * 8, co8 = (t1 & 7) * 8;
  int pb = half * 56;
  float m[8][8];
#pragma unroll
  for (int i = 0; i < 8; ++i)
#pragma unroll
    for (int j = 0; j < 8; ++j) m[i][j] = -3.4e38f;
  for (int pp = 0; pp < 56; pp += 2) {
    int p = pb + pp;
    ushort8 xs0 = *reinterpret_cast<const ushort8*>(&xls[p * XPAD + ci8]);
    ushort8 xs1 = *reinterpret_cast<const ushort8*>(&xls[(p + 1) * XPAD + ci8]);
    f32x4 a00 = *reinterpret_cast<const f32x4*>(&aml[p * APAD + co8]);
    f32x4 a01 = *reinterpret_cast<const f32x4*>(&aml[p * APAD + co8 + 4]);
    f32x4 a10 = *reinterpret_cast<const f32x4*>(&aml[(p + 1) * APAD + co8]);
    f32x4 a11 = *reinterpret_cast<const f32x4*>(&aml[(p + 1) * APAD + co8 + 4]);
    float xv0[8], xv1[8], av0[8], av1[8];
#pragma unroll
    for (int i = 0; i < 8; ++i) { xv0[i] = bf2f(xs0[i]); xv1[i] = bf2f(xs1[i]); }
#pragma unroll
    for (int j = 0; j < 4; ++j) {
      av0[j] = a00[j]; av0[j + 4] = a01[j];
      av1[j] = a10[j]; av1[j + 4] = a11[j];
    }
#pragma unroll
    for (int i = 0; i < 8; ++i)
#pragma unroll
      for (int j = 0; j < 8; ++j)
        m[i][j] = fmaxf(fmaxf(m[i][j], xv0[i] * av0[j]), xv1[i] * av1[j]);
  }
  int pcc = pc * 2 + half;
#pragma unroll
  for (int i = 0; i < 8; ++i) {
    f32x4 v0 = {m[i][0], m[i][1], m[i][2], m[i][3]};
    f32x4 v1 = {m[i][4], m[i][5], m[i][6], m[i][7]};
    size_t o = ((size_t)((pcc * 8 + b) * 512 + ci0 + ci8 + i)) * 64 + co8;
    *reinterpret_cast<f32x4*>(pmax + o) = v0;
    *reinterpret_cast<f32x4*>(pmax + o + 4) = v1;
  }
}

// ---------------------------------------------------------------------------
// Kernel 4: combine 14 partial maxes -> x_pool output
// ---------------------------------------------------------------------------
__global__ __launch_bounds__(256, 1) void k_combine(
    const float* __restrict__ pmax, float* __restrict__ xpool) {
  size_t idx = ((size_t)blockIdx.x * 256 + threadIdx.x) * 4;   // 262144 floats
  f32x4 v = *reinterpret_cast<const f32x4*>(pmax + idx);
#pragma unroll
  for (int pcc = 1; pcc < 14; ++pcc) {
    f32x4 u = *reinterpret_cast<const f32x4*>(pmax + (size_t)pcc * 262144 + idx);
#pragma unroll
    for (int j = 0; j < 4; ++j) v[j] = fmaxf(v[j], u[j]);
  }
  *reinterpret_cast<f32x4*>(xpool + idx) = v;
}

// ---------------------------------------------------------------------------
// Kernel 5: fc6 split-K GEMV-8. grid 1024 = 8kc * 128rg.
// Register-light inner (f4 loaded once/step, w row-wise) + launch_bounds(256,4)
// -> VGPR<=128 -> 16 waves/CU -> one balanced round on the 134MB stream.
// ---------------------------------------------------------------------------
__global__ __launch_bounds__(256, 4) void k_fc6(
    const float* __restrict__ flat, const float* __restrict__ w6,
    float* __restrict__ part6) {
  __shared__ float red[4][8][66];
  int bid = blockIdx.x;
  int kc = bid & 7, rg = bid >> 3;
  int t = threadIdx.x, W = t >> 6, lane = t & 63;
  int r0 = rg * 8;
  float acc[8][8];
#pragma unroll
  for (int r = 0; r < 8; ++r)
#pragma unroll
    for (int b = 0; b < 8; ++b) acc[r][b] = 0.f;
  int kbase = kc * 4096 + t * 4;
#pragma unroll
  for (int step = 0; step < 4; ++step) {
    int k = kbase + step * 1024;
    f32x4 f4[8];
#pragma unroll
    for (int b = 0; b < 8; ++b)
      f4[b] = *reinterpret_cast<const f32x4*>(flat + (size_t)b * 32768 + k);
#pragma unroll
    for (int r = 0; r < 8; ++r) {
      f32x4 w4 = *reinterpret_cast<const f32x4*>(w6 + (size_t)(r0 + r) * 32768 + k);
#pragma unroll
      for (int b = 0; b < 8; ++b)
        acc[r][b] += w4[0] * f4[b][0] + w4[1] * f4[b][1] +
                     w4[2] * f4[b][2] + w4[3] * f4[b][3];
    }
  }
#pragma unroll
  for (int r = 0; r < 8; ++r)
#pragma unroll
    for (int b = 0; b < 8; ++b) {
      float v = acc[r][b];
      v += __shfl_down(v, 32, 64);
      v += __shfl_down(v, 16, 64);
      v += __shfl_down(v, 8, 64);
      acc[r][b] = v;
    }
  if (lane < 8) {
#pragma unroll
    for (int r = 0; r < 8; ++r)
#pragma unroll
      for (int b = 0; b < 8; ++b) red[W][lane][r * 8 + b] = acc[r][b];
  }
  __syncthreads();
  if (t < 64) {
    float sum = 0.f;
#pragma unroll
    for (int w = 0; w < 4; ++w)
#pragma unroll
      for (int l = 0; l < 8; ++l) sum += red[w][l][t];
    int r = t >> 3, b = t & 7;
    part6[(size_t)kc * 8192 + (r0 + r) * 8 + b] = sum;
  }
}

// ---------------------------------------------------------------------------
// Kernel 6: reduce fc6 partials + bias + relu -> h[b][r]
// ---------------------------------------------------------------------------
__global__ __launch_bounds__(256, 1) void k_h(
    const float* __restrict__ part6, const float* __restrict__ b6,
    float* __restrict__ h) {
  int idx = blockIdx.x * 256 + threadIdx.x;   // 8192
  int r = idx >> 3, b = idx & 7;
  float s = b6[r];
#pragma unroll
  for (int kc = 0; kc < 8; ++kc) s += part6[(size_t)kc * 8192 + r * 8 + b];
  h[b * 1024 + r] = fmaxf(s, 0.f);
}

// ---------------------------------------------------------------------------
// Kernel 7: fc7 wave-per-row + bias + relu -> out[b][r]
// ---------------------------------------------------------------------------
__global__ __launch_bounds__(256, 1) void k_fc7(
    const float* __restrict__ h, const float* __restrict__ w7,
    const float* __restrict__ b7, float* __restrict__ out) {
  int bid = blockIdx.x;                        // 256
  int t = threadIdx.x, W = t >> 6, lane = t & 63;
  int r = bid * 4 + W;
  float acc[8] = {0, 0, 0, 0, 0, 0, 0, 0};
#pragma unroll
  for (int step = 0; step < 4; ++step) {
    int k = step * 256 + lane * 4;
    f32x4 w4 = *reinterpret_cast<const f32x4*>(w7 + (size_t)r * 1024 + k);
#pragma unroll
    for (int b = 0; b < 8; ++b) {
      f32x4 h4 = *reinterpret_cast<const f32x4*>(h + b * 1024 + k);
      acc[b] += w4[0] * h4[0] + w4[1] * h4[1] + w4[2] * h4[2] + w4[3] * h4[3];
    }
  }
#pragma unroll
  for (int b = 0; b < 8; ++b) {
    float v = acc[b];
#pragma unroll
    for (int off = 32; off > 0; off >>= 1) v += __shfl_down(v, off, 64);
    acc[b] = v;
  }
  if (lane == 0) {
#pragma unroll
    for (int b = 0; b < 8; ++b) out[b * 1024 + r] = fmaxf(acc[b] + b7[r], 0.f);
  }
}

// ---------------------------------------------------------------------------
extern "C" void kernel_launch(void* const* d_in, const int* in_sizes, int n_in,
                              void* d_out, int out_size, void* d_ws, size_t ws_size,
                              hipStream_t stream) {
  const float* x  = (const float*)d_in[0];
  const float* cw = (const float*)d_in[1];
  const float* cb = (const float*)d_in[2];
  const float* w6 = (const float*)d_in[3];
  const float* b6 = (const float*)d_in[4];
  const float* w7 = (const float*)d_in[5];
  const float* b7 = (const float*)d_in[6];
  float* out   = (float*)d_out;            // (8,1024) = 8192
  float* xpool = out + 8192;               // (8,512,64) = 262144

  char* ws = (char*)d_ws;
  unsigned short* xT  = (unsigned short*)(ws);                 //  6,422,528 B
  unsigned short* wpk = (unsigned short*)(ws + 6422528);       //    589,824 B
  float* am_part      = (float*)(ws + 7012352);                //  6,422,528 B
  float* pmax         = (float*)(ws + 13434880);               // 14,680,064 B
  float* part6        = (float*)(ws + 28114944);               //    262,144 B
  float* hbuf         = (float*)(ws + 28377088);               //     32,768 B

  hipLaunchKernelGGL(k_xpose,   dim3(968),  dim3(256), 0, stream, x, cw, xT, wpk);
  hipLaunchKernelGGL(k_conv,    dim3(448),  dim3(128), 0, stream, xT, wpk, cb, am_part);
  hipLaunchKernelGGL(k_pool,    dim3(224),  dim3(256), 0, stream, xT, am_part, pmax);
  hipLaunchKernelGGL(k_combine, dim3(256),  dim3(256), 0, stream, pmax, xpool);
  hipLaunchKernelGGL(k_fc6,     dim3(1024), dim3(256), 0, stream, xpool, w6, part6);
  hipLaunchKernelGGL(k_h,       dim3(32),   dim3(256), 0, stream, part6, b6, hbuf);
  hipLaunchKernelGGL(k_fc7,     dim3(256),  dim3(256), 0, stream, hbuf, w7, b7, out);
}

// Round 4
// 108.849 us; speedup vs baseline: 3.3451x; 3.3451x over previous
//
#include <hip/hip_runtime.h>

typedef __attribute__((ext_vector_type(4))) float f32x4;
typedef __attribute__((ext_vector_type(8))) __bf16 bf16x8;
typedef __attribute__((ext_vector_type(8))) unsigned short ushort8;

static __device__ __forceinline__ unsigned short f2bf(float f) {
  unsigned u = __float_as_uint(f);
  u += 0x7fffu + ((u >> 16) & 1u);   // RNE
  return (unsigned short)(u >> 16);
}
static __device__ __forceinline__ float bf2f(unsigned short s) {
  return __uint_as_float(((unsigned)s) << 16);
}

// ---------------------------------------------------------------------------
// Kernel 1: LDS-tiled transpose x[b][ci][p] (f32) -> xT[b][p][ci] (bf16),
// plus weight repack conv_w[co][ci][3][3] -> wpk[tap][co][ci] (bf16).
// ---------------------------------------------------------------------------
__global__ __launch_bounds__(256, 1) void k_xpose(
    const float* __restrict__ x, const float* __restrict__ cw,
    unsigned short* __restrict__ xT, unsigned short* __restrict__ wpk) {
  int bid = blockIdx.x;
  int t = threadIdx.x;
  if (bid < 896) {
    __shared__ float xl[64 * 57];            // [ci 64][p 56 pad 57]
    int pt = bid % 14, cit = (bid / 14) & 7, b = bid / 112;
    int p0 = pt * 56, ci0 = cit * 64;
#pragma unroll
    for (int i = 0; i < 4; ++i) {            // 896 f32x4 coalesced reads
      int idx = i * 256 + t;
      if (idx < 896) {
        int ci = idx / 14, p4 = (idx % 14) * 4;
        f32x4 v = *reinterpret_cast<const f32x4*>(
            x + ((size_t)(b * 512 + ci0 + ci)) * 784 + p0 + p4);
        *reinterpret_cast<f32x4*>(&xl[ci * 57 + p4]) = v;
      }
    }
    __syncthreads();
#pragma unroll
    for (int i = 0; i < 2; ++i) {            // 448 ushort8 coalesced writes
      int idx = i * 256 + t;
      if (idx < 448) {
        int p = idx >> 3, c8 = (idx & 7) * 8;
        ushort8 o;
#pragma unroll
        for (int j = 0; j < 8; ++j) o[j] = f2bf(xl[(c8 + j) * 57 + p]);
        *reinterpret_cast<ushort8*>(
            xT + ((size_t)(b * 784 + p0 + p)) * 512 + ci0 + c8) = o;
      }
    }
  } else {                                   // 72 blocks * 4096 = 294912 wpk elems
    int o0 = (bid - 896) * 4096 + t * 16;
    ushort8 w0, w1;
#pragma unroll
    for (int j = 0; j < 16; ++j) {
      int o = o0 + j;
      int ci = o & 511, co = (o >> 9) & 63, tap = o >> 15;
      unsigned short v = f2bf(cw[((size_t)(co * 512 + ci)) * 9 + tap]);
      if (j < 8) w0[j] = v; else w1[j - 8] = v;
    }
    *reinterpret_cast<ushort8*>(wpk + o0) = w0;
    *reinterpret_cast<ushort8*>(wpk + o0 + 8) = w1;
  }
}

// ---------------------------------------------------------------------------
// Kernel 2: conv3x3 via bf16 MFMA, tap-decomposed implicit GEMM.
// grid 448 = 8b * 7px * 2co2 * 4split ; block 128 (2 waves)
// bias folded into the s==0 accumulator init. writes am_part[s][b][p][co]
// ---------------------------------------------------------------------------
#define CPAD 56
__global__ __launch_bounds__(128, 1) void k_conv(
    const unsigned short* __restrict__ xT, const unsigned short* __restrict__ wpk,
    const float* __restrict__ cb, float* __restrict__ am_part) {
  __shared__ unsigned short wl[9 * 32 * CPAD];  // [tap][co_l 32][ci 32 pad 56]
  __shared__ unsigned short xl[168 * CPAD];     // [pos 6rows*28][ci 32 pad 56]
  int bid = blockIdx.x;
  int s  = bid & 3;
  int c2 = (bid >> 2) & 1;
  int px = (bid >> 3) % 7;
  int b  = bid / 56;
  int t = threadIdx.x;
  int W = t >> 6, lane = t & 63;
  int co_base = c2 * 32;
  int p0 = px * 112, h0 = px * 4;
  int n = lane & 15, kg = lane >> 4;

  int lrow0[7], wc[7];
#pragma unroll
  for (int f = 0; f < 7; ++f) {
    int pit = f * 16 + n;
    lrow0[f] = pit / 28 + 1;
    wc[f]    = pit % 28;
  }
  f32x4 acc[7];
  f32x4 cb4 = {0.f, 0.f, 0.f, 0.f};
  if (s == 0)
    cb4 = *reinterpret_cast<const f32x4*>(cb + co_base + W * 16 + kg * 4);
#pragma unroll
  for (int f = 0; f < 7; ++f) acc[f] = cb4;
  const ushort8 bzero = {0, 0, 0, 0, 0, 0, 0, 0};

  for (int c = 0; c < 4; ++c) {           // 4 ci-chunks of 32 (split covers 128 ci)
    int ci_c = s * 128 + c * 32;
    __syncthreads();
#pragma unroll
    for (int i = 0; i < 9; ++i) {         // stage weights
      int q = i * 128 + t;
      int tapco = q >> 2, ci8 = (q & 3) * 8;
      int tap = tapco >> 5, co_l = tapco & 31;
      ushort8 v = *reinterpret_cast<const ushort8*>(
          wpk + ((size_t)(tap * 64 + co_base + co_l)) * 512 + ci_c + ci8);
      *reinterpret_cast<ushort8*>(&wl[(tap * 32 + co_l) * CPAD + ci8]) = v;
    }
#pragma unroll
    for (int i = 0; i < 6; ++i) {         // stage x halo tile
      int q = i * 128 + t;
      if (q < 672) {
        int pos = q >> 2, ci8 = (q & 3) * 8;
        int lr = pos / 28, c_ = pos % 28;
        int h = h0 - 1 + lr;
        ushort8 v = bzero;
        if (h >= 0 && h < 28)
          v = *reinterpret_cast<const ushort8*>(
              xT + ((size_t)(b * 784 + h * 28 + c_)) * 512 + ci_c + ci8);
        *reinterpret_cast<ushort8*>(&xl[pos * CPAD + ci8]) = v;
      }
    }
    __syncthreads();
#pragma unroll
    for (int tap = 0; tap < 9; ++tap) {
      int dh = tap / 3 - 1, dw = tap % 3 - 1;
      bf16x8 a = *reinterpret_cast<const bf16x8*>(
          &wl[(tap * 32 + W * 16 + n) * CPAD + kg * 8]);
#pragma unroll
      for (int f = 0; f < 7; ++f) {
        int wcd = wc[f] + dw;
        bool valid = (unsigned)wcd < 28u;
        int pos = (lrow0[f] + dh) * 28 + wcd;
        int posc = valid ? pos : 0;
        ushort8 bv = *reinterpret_cast<const ushort8*>(&xl[posc * CPAD + kg * 8]);
        if (!valid) bv = bzero;
        acc[f] = __builtin_amdgcn_mfma_f32_16x16x32_bf16(
            a, __builtin_bit_cast(bf16x8, bv), acc[f], 0, 0, 0);
      }
    }
  }
#pragma unroll
  for (int f = 0; f < 7; ++f) {
    int p  = p0 + f * 16 + n;
    int co = co_base + W * 16 + kg * 4;
    *reinterpret_cast<f32x4*>(
        am_part + ((size_t)((s * 8 + b) * 784 + p)) * 64 + co) = acc[f];
  }
}

// ---------------------------------------------------------------------------
// Kernel 3: outer-product partial max-pool.
// grid 224 = 8b * 4cit * 7pc ; block 256. Tile: 128ci x 64co x 112p.
// writes pmax[pcc 14][b][ci][co]
// ---------------------------------------------------------------------------
#define XPAD 144   // shorts per p-row (288 B)
#define APAD 72    // floats per p-row (288 B)
__global__ __launch_bounds__(256, 1) void k_pool(
    const unsigned short* __restrict__ xT, const float* __restrict__ am_part,
    float* __restrict__ pmax) {
  __shared__ unsigned short xls[112 * XPAD]; // 32256 B  [p][ci 128]
  __shared__ float aml[112 * APAD];          // 32256 B  [p][co 64]
  int bid = blockIdx.x;
  int pc  = bid % 7;
  int cit = (bid / 7) & 3;
  int b   = bid / 28;
  int t = threadIdx.x;
  int p0 = pc * 112, ci0 = cit * 128;
#pragma unroll
  for (int i = 0; i < 7; ++i) {      // stage xT tile: 1792 ushort8
    int idx = i * 256 + t;
    int p = idx >> 4, c8 = (idx & 15) * 8;
    ushort8 v = *reinterpret_cast<const ushort8*>(
        xT + ((size_t)(b * 784 + p0 + p)) * 512 + ci0 + c8);
    *reinterpret_cast<ushort8*>(&xls[p * XPAD + c8]) = v;
  }
#pragma unroll
  for (int i = 0; i < 7; ++i) {      // stage am tile: 1792 f32x4, sum 4 splits
    int idx = i * 256 + t;
    int p = idx >> 4, co4 = (idx & 15) * 4;
    size_t o0 = ((size_t)(b * 784 + p0 + p)) * 64 + co4;
    f32x4 v = *reinterpret_cast<const f32x4*>(am_part + o0);
#pragma unroll
    for (int s2 = 1; s2 < 4; ++s2)
      v = v + *reinterpret_cast<const f32x4*>(am_part + o0 + (size_t)s2 * 8 * 784 * 64);
    *reinterpret_cast<f32x4*>(&aml[p * APAD + co4]) = v;
  }
  __syncthreads();
  int half = t >> 7;                 // p-half: 0 -> p 0..55, 1 -> p 56..111
  int t1 = t & 127;
  int ci8 = (t1 >> 3) * 8, co8 = (t1 & 7) * 8;
  int pb = half * 56;
  float m[8][8];
#pragma unroll
  for (int i = 0; i < 8; ++i)
#pragma unroll
    for (int j = 0; j < 8; ++j) m[i][j] = -3.4e38f;
  for (int pp = 0; pp < 56; pp += 2) {
    int p = pb + pp;
    ushort8 xs0 = *reinterpret_cast<const ushort8*>(&xls[p * XPAD + ci8]);
    ushort8 xs1 = *reinterpret_cast<const ushort8*>(&xls[(p + 1) * XPAD + ci8]);
    f32x4 a00 = *reinterpret_cast<const f32x4*>(&aml[p * APAD + co8]);
    f32x4 a01 = *reinterpret_cast<const f32x4*>(&aml[p * APAD + co8 + 4]);
    f32x4 a10 = *reinterpret_cast<const f32x4*>(&aml[(p + 1) * APAD + co8]);
    f32x4 a11 = *reinterpret_cast<const f32x4*>(&aml[(p + 1) * APAD + co8 + 4]);
    float xv0[8], xv1[8], av0[8], av1[8];
#pragma unroll
    for (int i = 0; i < 8; ++i) { xv0[i] = bf2f(xs0[i]); xv1[i] = bf2f(xs1[i]); }
#pragma unroll
    for (int j = 0; j < 4; ++j) {
      av0[j] = a00[j]; av0[j + 4] = a01[j];
      av1[j] = a10[j]; av1[j + 4] = a11[j];
    }
#pragma unroll
    for (int i = 0; i < 8; ++i)
#pragma unroll
      for (int j = 0; j < 8; ++j)
        m[i][j] = fmaxf(fmaxf(m[i][j], xv0[i] * av0[j]), xv1[i] * av1[j]);
  }
  int pcc = pc * 2 + half;
#pragma unroll
  for (int i = 0; i < 8; ++i) {
    f32x4 v0 = {m[i][0], m[i][1], m[i][2], m[i][3]};
    f32x4 v1 = {m[i][4], m[i][5], m[i][6], m[i][7]};
    size_t o = ((size_t)((pcc * 8 + b) * 512 + ci0 + ci8 + i)) * 64 + co8;
    *reinterpret_cast<f32x4*>(pmax + o) = v0;
    *reinterpret_cast<f32x4*>(pmax + o + 4) = v1;
  }
}

// ---------------------------------------------------------------------------
// Kernel 4: combine 14 partial maxes -> x_pool output
// ---------------------------------------------------------------------------
__global__ __launch_bounds__(256, 1) void k_combine(
    const float* __restrict__ pmax, float* __restrict__ xpool) {
  size_t idx = ((size_t)blockIdx.x * 256 + threadIdx.x) * 4;   // 262144 floats
  f32x4 v = *reinterpret_cast<const f32x4*>(pmax + idx);
#pragma unroll
  for (int pcc = 1; pcc < 14; ++pcc) {
    f32x4 u = *reinterpret_cast<const f32x4*>(pmax + (size_t)pcc * 262144 + idx);
#pragma unroll
    for (int j = 0; j < 4; ++j) v[j] = fmaxf(v[j], u[j]);
  }
  *reinterpret_cast<f32x4*>(xpool + idx) = v;
}

// ---------------------------------------------------------------------------
// Kernel 5: fc6 split-K GEMV-8. grid 1024 = 8kc * 128rg.
// acc[8][8] (64 regs live) -> NO tight VGPR cap (round-3's (256,4) forced
// VGPR=64 and spilled ~850MB to scratch: 491MB FETCH / 486MB WRITE).
// (256,2) caps at 256 VGPR; compiler should land ~115 -> 16 waves/CU.
// ---------------------------------------------------------------------------
__global__ __launch_bounds__(256, 2) void k_fc6(
    const float* __restrict__ flat, const float* __restrict__ w6,
    float* __restrict__ part6) {
  __shared__ float red[4][8][66];
  int bid = blockIdx.x;
  int kc = bid & 7, rg = bid >> 3;
  int t = threadIdx.x, W = t >> 6, lane = t & 63;
  int r0 = rg * 8;
  float acc[8][8];
#pragma unroll
  for (int r = 0; r < 8; ++r)
#pragma unroll
    for (int b = 0; b < 8; ++b) acc[r][b] = 0.f;
  int kbase = kc * 4096 + t * 4;
#pragma unroll
  for (int step = 0; step < 4; ++step) {
    int k = kbase + step * 1024;
    f32x4 f4[8];
#pragma unroll
    for (int b = 0; b < 8; ++b)
      f4[b] = *reinterpret_cast<const f32x4*>(flat + (size_t)b * 32768 + k);
#pragma unroll
    for (int r = 0; r < 8; ++r) {
      f32x4 w4 = *reinterpret_cast<const f32x4*>(w6 + (size_t)(r0 + r) * 32768 + k);
#pragma unroll
      for (int b = 0; b < 8; ++b)
        acc[r][b] += w4[0] * f4[b][0] + w4[1] * f4[b][1] +
                     w4[2] * f4[b][2] + w4[3] * f4[b][3];
    }
  }
#pragma unroll
  for (int r = 0; r < 8; ++r)
#pragma unroll
    for (int b = 0; b < 8; ++b) {
      float v = acc[r][b];
      v += __shfl_down(v, 32, 64);
      v += __shfl_down(v, 16, 64);
      v += __shfl_down(v, 8, 64);
      acc[r][b] = v;
    }
  if (lane < 8) {
#pragma unroll
    for (int r = 0; r < 8; ++r)
#pragma unroll
      for (int b = 0; b < 8; ++b) red[W][lane][r * 8 + b] = acc[r][b];
  }
  __syncthreads();
  if (t < 64) {
    float sum = 0.f;
#pragma unroll
    for (int w = 0; w < 4; ++w)
#pragma unroll
      for (int l = 0; l < 8; ++l) sum += red[w][l][t];
    int r = t >> 3, b = t & 7;
    part6[(size_t)kc * 8192 + (r0 + r) * 8 + b] = sum;
  }
}

// ---------------------------------------------------------------------------
// Kernel 6: reduce fc6 partials + bias + relu -> h[b][r]
// ---------------------------------------------------------------------------
__global__ __launch_bounds__(256, 1) void k_h(
    const float* __restrict__ part6, const float* __restrict__ b6,
    float* __restrict__ h) {
  int idx = blockIdx.x * 256 + threadIdx.x;   // 8192
  int r = idx >> 3, b = idx & 7;
  float s = b6[r];
#pragma unroll
  for (int kc = 0; kc < 8; ++kc) s += part6[(size_t)kc * 8192 + r * 8 + b];
  h[b * 1024 + r] = fmaxf(s, 0.f);
}

// ---------------------------------------------------------------------------
// Kernel 7: fc7 wave-per-row + bias + relu -> out[b][r]
// ---------------------------------------------------------------------------
__global__ __launch_bounds__(256, 1) void k_fc7(
    const float* __restrict__ h, const float* __restrict__ w7,
    const float* __restrict__ b7, float* __restrict__ out) {
  int bid = blockIdx.x;                        // 256
  int t = threadIdx.x, W = t >> 6, lane = t & 63;
  int r = bid * 4 + W;
  float acc[8] = {0, 0, 0, 0, 0, 0, 0, 0};
#pragma unroll
  for (int step = 0; step < 4; ++step) {
    int k = step * 256 + lane * 4;
    f32x4 w4 = *reinterpret_cast<const f32x4*>(w7 + (size_t)r * 1024 + k);
#pragma unroll
    for (int b = 0; b < 8; ++b) {
      f32x4 h4 = *reinterpret_cast<const f32x4*>(h + b * 1024 + k);
      acc[b] += w4[0] * h4[0] + w4[1] * h4[1] + w4[2] * h4[2] + w4[3] * h4[3];
    }
  }
#pragma unroll
  for (int b = 0; b < 8; ++b) {
    float v = acc[b];
#pragma unroll
    for (int off = 32; off > 0; off >>= 1) v += __shfl_down(v, off, 64);
    acc[b] = v;
  }
  if (lane == 0) {
#pragma unroll
    for (int b = 0; b < 8; ++b) out[b * 1024 + r] = fmaxf(acc[b] + b7[r], 0.f);
  }
}

// ---------------------------------------------------------------------------
extern "C" void kernel_launch(void* const* d_in, const int* in_sizes, int n_in,
                              void* d_out, int out_size, void* d_ws, size_t ws_size,
                              hipStream_t stream) {
  const float* x  = (const float*)d_in[0];
  const float* cw = (const float*)d_in[1];
  const float* cb = (const float*)d_in[2];
  const float* w6 = (const float*)d_in[3];
  const float* b6 = (const float*)d_in[4];
  const float* w7 = (const float*)d_in[5];
  const float* b7 = (const float*)d_in[6];
  float* out   = (float*)d_out;            // (8,1024) = 8192
  float* xpool = out + 8192;               // (8,512,64) = 262144

  char* ws = (char*)d_ws;
  unsigned short* xT  = (unsigned short*)(ws);                 //  6,422,528 B
  unsigned short* wpk = (unsigned short*)(ws + 6422528);       //    589,824 B
  float* am_part      = (float*)(ws + 7012352);                //  6,422,528 B
  float* pmax         = (float*)(ws + 13434880);               // 14,680,064 B
  float* part6        = (float*)(ws + 28114944);               //    262,144 B
  float* hbuf         = (float*)(ws + 28377088);               //     32,768 B

  hipLaunchKernelGGL(k_xpose,   dim3(968),  dim3(256), 0, stream, x, cw, xT, wpk);
  hipLaunchKernelGGL(k_conv,    dim3(448),  dim3(128), 0, stream, xT, wpk, cb, am_part);
  hipLaunchKernelGGL(k_pool,    dim3(224),  dim3(256), 0, stream, xT, am_part, pmax);
  hipLaunchKernelGGL(k_combine, dim3(256),  dim3(256), 0, stream, pmax, xpool);
  hipLaunchKernelGGL(k_fc6,     dim3(1024), dim3(256), 0, stream, xpool, w6, part6);
  hipLaunchKernelGGL(k_h,       dim3(32),   dim3(256), 0, stream, part6, b6, hbuf);
  hipLaunchKernelGGL(k_fc7,     dim3(256),  dim3(256), 0, stream, hbuf, w7, b7, out);
}

// Round 5
// 82.600 us; speedup vs baseline: 4.4082x; 1.3178x over previous
//
#include <hip/hip_runtime.h>

typedef __attribute__((ext_vector_type(4))) float f32x4;
typedef __attribute__((ext_vector_type(8))) __bf16 bf16x8;
typedef __attribute__((ext_vector_type(8))) unsigned short ushort8;

static __device__ __forceinline__ unsigned short f2bf(float f) {
  unsigned u = __float_as_uint(f);
  u += 0x7fffu + ((u >> 16) & 1u);   // RNE
  return (unsigned short)(u >> 16);
}
static __device__ __forceinline__ float bf2f(unsigned short s) {
  return __uint_as_float(((unsigned)s) << 16);
}

// ---------------------------------------------------------------------------
// Kernel 1: LDS-tiled transpose x[b][ci][p] (f32) -> xT[b][p][ci] (bf16),
// plus weight repack conv_w[co][ci][3][3] -> wpk[tap][co][ci] (bf16).
// ---------------------------------------------------------------------------
__global__ __launch_bounds__(256, 1) void k_xpose(
    const float* __restrict__ x, const float* __restrict__ cw,
    unsigned short* __restrict__ xT, unsigned short* __restrict__ wpk) {
  int bid = blockIdx.x;
  int t = threadIdx.x;
  if (bid < 896) {
    __shared__ float xl[64 * 57];            // [ci 64][p 56 pad 57]
    int pt = bid % 14, cit = (bid / 14) & 7, b = bid / 112;
    int p0 = pt * 56, ci0 = cit * 64;
#pragma unroll
    for (int i = 0; i < 4; ++i) {            // 896 f32x4 coalesced reads
      int idx = i * 256 + t;
      if (idx < 896) {
        int ci = idx / 14, p4 = (idx % 14) * 4;
        f32x4 v = *reinterpret_cast<const f32x4*>(
            x + ((size_t)(b * 512 + ci0 + ci)) * 784 + p0 + p4);
        *reinterpret_cast<f32x4*>(&xl[ci * 57 + p4]) = v;
      }
    }
    __syncthreads();
#pragma unroll
    for (int i = 0; i < 2; ++i) {            // 448 ushort8 coalesced writes
      int idx = i * 256 + t;
      if (idx < 448) {
        int p = idx >> 3, c8 = (idx & 7) * 8;
        ushort8 o;
#pragma unroll
        for (int j = 0; j < 8; ++j) o[j] = f2bf(xl[(c8 + j) * 57 + p]);
        *reinterpret_cast<ushort8*>(
            xT + ((size_t)(b * 784 + p0 + p)) * 512 + ci0 + c8) = o;
      }
    }
  } else {                                   // 72 blocks * 4096 = 294912 wpk elems
    int o0 = (bid - 896) * 4096 + t * 16;
    ushort8 w0, w1;
#pragma unroll
    for (int j = 0; j < 16; ++j) {
      int o = o0 + j;
      int ci = o & 511, co = (o >> 9) & 63, tap = o >> 15;
      unsigned short v = f2bf(cw[((size_t)(co * 512 + ci)) * 9 + tap]);
      if (j < 8) w0[j] = v; else w1[j - 8] = v;
    }
    *reinterpret_cast<ushort8*>(wpk + o0) = w0;
    *reinterpret_cast<ushort8*>(wpk + o0 + 8) = w1;
  }
}

// ---------------------------------------------------------------------------
// Kernel 2: conv3x3 via bf16 MFMA, tap-decomposed implicit GEMM.
// grid 448 = 8b * 7px * 2co2 * 4split ; block 128 (2 waves)
// bias folded into the s==0 accumulator init. writes am_part[s][b][p][co]
// ---------------------------------------------------------------------------
#define CPAD 56
__global__ __launch_bounds__(128, 1) void k_conv(
    const unsigned short* __restrict__ xT, const unsigned short* __restrict__ wpk,
    const float* __restrict__ cb, float* __restrict__ am_part) {
  __shared__ unsigned short wl[9 * 32 * CPAD];  // [tap][co_l 32][ci 32 pad 56]
  __shared__ unsigned short xl[168 * CPAD];     // [pos 6rows*28][ci 32 pad 56]
  int bid = blockIdx.x;
  int s  = bid & 3;
  int c2 = (bid >> 2) & 1;
  int px = (bid >> 3) % 7;
  int b  = bid / 56;
  int t = threadIdx.x;
  int W = t >> 6, lane = t & 63;
  int co_base = c2 * 32;
  int p0 = px * 112, h0 = px * 4;
  int n = lane & 15, kg = lane >> 4;

  int lrow0[7], wc[7];
#pragma unroll
  for (int f = 0; f < 7; ++f) {
    int pit = f * 16 + n;
    lrow0[f] = pit / 28 + 1;
    wc[f]    = pit % 28;
  }
  f32x4 acc[7];
  f32x4 cb4 = {0.f, 0.f, 0.f, 0.f};
  if (s == 0)
    cb4 = *reinterpret_cast<const f32x4*>(cb + co_base + W * 16 + kg * 4);
#pragma unroll
  for (int f = 0; f < 7; ++f) acc[f] = cb4;
  const ushort8 bzero = {0, 0, 0, 0, 0, 0, 0, 0};

  for (int c = 0; c < 4; ++c) {           // 4 ci-chunks of 32 (split covers 128 ci)
    int ci_c = s * 128 + c * 32;
    __syncthreads();
#pragma unroll
    for (int i = 0; i < 9; ++i) {         // stage weights
      int q = i * 128 + t;
      int tapco = q >> 2, ci8 = (q & 3) * 8;
      int tap = tapco >> 5, co_l = tapco & 31;
      ushort8 v = *reinterpret_cast<const ushort8*>(
          wpk + ((size_t)(tap * 64 + co_base + co_l)) * 512 + ci_c + ci8);
      *reinterpret_cast<ushort8*>(&wl[(tap * 32 + co_l) * CPAD + ci8]) = v;
    }
#pragma unroll
    for (int i = 0; i < 6; ++i) {         // stage x halo tile
      int q = i * 128 + t;
      if (q < 672) {
        int pos = q >> 2, ci8 = (q & 3) * 8;
        int lr = pos / 28, c_ = pos % 28;
        int h = h0 - 1 + lr;
        ushort8 v = bzero;
        if (h >= 0 && h < 28)
          v = *reinterpret_cast<const ushort8*>(
              xT + ((size_t)(b * 784 + h * 28 + c_)) * 512 + ci_c + ci8);
        *reinterpret_cast<ushort8*>(&xl[pos * CPAD + ci8]) = v;
      }
    }
    __syncthreads();
#pragma unroll
    for (int tap = 0; tap < 9; ++tap) {
      int dh = tap / 3 - 1, dw = tap % 3 - 1;
      bf16x8 a = *reinterpret_cast<const bf16x8*>(
          &wl[(tap * 32 + W * 16 + n) * CPAD + kg * 8]);
#pragma unroll
      for (int f = 0; f < 7; ++f) {
        int wcd = wc[f] + dw;
        bool valid = (unsigned)wcd < 28u;
        int pos = (lrow0[f] + dh) * 28 + wcd;
        int posc = valid ? pos : 0;
        ushort8 bv = *reinterpret_cast<const ushort8*>(&xl[posc * CPAD + kg * 8]);
        if (!valid) bv = bzero;
        acc[f] = __builtin_amdgcn_mfma_f32_16x16x32_bf16(
            a, __builtin_bit_cast(bf16x8, bv), acc[f], 0, 0, 0);
      }
    }
  }
#pragma unroll
  for (int f = 0; f < 7; ++f) {
    int p  = p0 + f * 16 + n;
    int co = co_base + W * 16 + kg * 4;
    *reinterpret_cast<f32x4*>(
        am_part + ((size_t)((s * 8 + b) * 784 + p)) * 64 + co) = acc[f];
  }
}

// ---------------------------------------------------------------------------
// Kernel 3: outer-product partial max-pool.
// grid 224 = 8b * 4cit * 7pc ; block 256. Tile: 128ci x 64co x 112p.
// writes pmax[pcc 14][b][ci][co]
// ---------------------------------------------------------------------------
#define XPAD 144   // shorts per p-row (288 B)
#define APAD 72    // floats per p-row (288 B)
__global__ __launch_bounds__(256, 1) void k_pool(
    const unsigned short* __restrict__ xT, const float* __restrict__ am_part,
    float* __restrict__ pmax) {
  __shared__ unsigned short xls[112 * XPAD]; // 32256 B  [p][ci 128]
  __shared__ float aml[112 * APAD];          // 32256 B  [p][co 64]
  int bid = blockIdx.x;
  int pc  = bid % 7;
  int cit = (bid / 7) & 3;
  int b   = bid / 28;
  int t = threadIdx.x;
  int p0 = pc * 112, ci0 = cit * 128;
#pragma unroll
  for (int i = 0; i < 7; ++i) {      // stage xT tile: 1792 ushort8
    int idx = i * 256 + t;
    int p = idx >> 4, c8 = (idx & 15) * 8;
    ushort8 v = *reinterpret_cast<const ushort8*>(
        xT + ((size_t)(b * 784 + p0 + p)) * 512 + ci0 + c8);
    *reinterpret_cast<ushort8*>(&xls[p * XPAD + c8]) = v;
  }
#pragma unroll
  for (int i = 0; i < 7; ++i) {      // stage am tile: 1792 f32x4, sum 4 splits
    int idx = i * 256 + t;
    int p = idx >> 4, co4 = (idx & 15) * 4;
    size_t o0 = ((size_t)(b * 784 + p0 + p)) * 64 + co4;
    f32x4 v = *reinterpret_cast<const f32x4*>(am_part + o0);
#pragma unroll
    for (int s2 = 1; s2 < 4; ++s2)
      v = v + *reinterpret_cast<const f32x4*>(am_part + o0 + (size_t)s2 * 8 * 784 * 64);
    *reinterpret_cast<f32x4*>(&aml[p * APAD + co4]) = v;
  }
  __syncthreads();
  int half = t >> 7;                 // p-half: 0 -> p 0..55, 1 -> p 56..111
  int t1 = t & 127;
  int ci8 = (t1 >> 3) * 8, co8 = (t1 & 7) * 8;
  int pb = half * 56;
  float m[8][8];
#pragma unroll
  for (int i = 0; i < 8; ++i)
#pragma unroll
    for (int j = 0; j < 8; ++j) m[i][j] = -3.4e38f;
  for (int pp = 0; pp < 56; pp += 2) {
    int p = pb + pp;
    ushort8 xs0 = *reinterpret_cast<const ushort8*>(&xls[p * XPAD + ci8]);
    ushort8 xs1 = *reinterpret_cast<const ushort8*>(&xls[(p + 1) * XPAD + ci8]);
    f32x4 a00 = *reinterpret_cast<const f32x4*>(&aml[p * APAD + co8]);
    f32x4 a01 = *reinterpret_cast<const f32x4*>(&aml[p * APAD + co8 + 4]);
    f32x4 a10 = *reinterpret_cast<const f32x4*>(&aml[(p + 1) * APAD + co8]);
    f32x4 a11 = *reinterpret_cast<const f32x4*>(&aml[(p + 1) * APAD + co8 + 4]);
    float xv0[8], xv1[8], av0[8], av1[8];
#pragma unroll
    for (int i = 0; i < 8; ++i) { xv0[i] = bf2f(xs0[i]); xv1[i] = bf2f(xs1[i]); }
#pragma unroll
    for (int j = 0; j < 4; ++j) {
      av0[j] = a00[j]; av0[j + 4] = a01[j];
      av1[j] = a10[j]; av1[j + 4] = a11[j];
    }
#pragma unroll
    for (int i = 0; i < 8; ++i)
#pragma unroll
      for (int j = 0; j < 8; ++j)
        m[i][j] = fmaxf(fmaxf(m[i][j], xv0[i] * av0[j]), xv1[i] * av1[j]);
  }
  int pcc = pc * 2 + half;
#pragma unroll
  for (int i = 0; i < 8; ++i) {
    f32x4 v0 = {m[i][0], m[i][1], m[i][2], m[i][3]};
    f32x4 v1 = {m[i][4], m[i][5], m[i][6], m[i][7]};
    size_t o = ((size_t)((pcc * 8 + b) * 512 + ci0 + ci8 + i)) * 64 + co8;
    *reinterpret_cast<f32x4*>(pmax + o) = v0;
    *reinterpret_cast<f32x4*>(pmax + o + 4) = v1;
  }
}

// ---------------------------------------------------------------------------
// Kernel 4: combine 14 partial maxes -> x_pool output
// ---------------------------------------------------------------------------
__global__ __launch_bounds__(256, 1) void k_combine(
    const float* __restrict__ pmax, float* __restrict__ xpool) {
  size_t idx = ((size_t)blockIdx.x * 256 + threadIdx.x) * 4;   // 262144 floats
  f32x4 v = *reinterpret_cast<const f32x4*>(pmax + idx);
#pragma unroll
  for (int pcc = 1; pcc < 14; ++pcc) {
    f32x4 u = *reinterpret_cast<const f32x4*>(pmax + (size_t)pcc * 262144 + idx);
#pragma unroll
    for (int j = 0; j < 4; ++j) v[j] = fmaxf(v[j], u[j]);
  }
  *reinterpret_cast<f32x4*>(xpool + idx) = v;
}

// ---------------------------------------------------------------------------
// Kernel 5: fc6 split-K GEMV-8. grid 2048 = 8kc * 256rg; 4 rows x 8 batches/thr.
// acc[4][8]=32 + f4[8]=32 + w4[4]=16 ≈ 96 live VGPR -> no spill (R4 lesson:
// VGPR=128 + full unroll spilled 67MB). unroll 1 on the k-step loop prevents
// the scheduler from keeping two steps' load sets live.
// ---------------------------------------------------------------------------
__global__ __launch_bounds__(256) void k_fc6(
    const float* __restrict__ flat, const float* __restrict__ w6,
    float* __restrict__ part6) {
  __shared__ float red[4][8][33];
  int bid = blockIdx.x;
  int kc = bid & 7, rg = bid >> 3;          // rg 0..255
  int t = threadIdx.x, W = t >> 6, lane = t & 63;
  int r0 = rg * 4;
  float acc[4][8];
#pragma unroll
  for (int r = 0; r < 4; ++r)
#pragma unroll
    for (int b = 0; b < 8; ++b) acc[r][b] = 0.f;
  int kbase = kc * 4096 + t * 4;
#pragma unroll 1
  for (int step = 0; step < 4; ++step) {
    int k = kbase + step * 1024;
    f32x4 f4[8];
#pragma unroll
    for (int b = 0; b < 8; ++b)
      f4[b] = *reinterpret_cast<const f32x4*>(flat + (size_t)b * 32768 + k);
    f32x4 w4[4];
#pragma unroll
    for (int r = 0; r < 4; ++r)
      w4[r] = *reinterpret_cast<const f32x4*>(w6 + (size_t)(r0 + r) * 32768 + k);
#pragma unroll
    for (int r = 0; r < 4; ++r)
#pragma unroll
      for (int b = 0; b < 8; ++b)
        acc[r][b] += w4[r][0] * f4[b][0] + w4[r][1] * f4[b][1] +
                     w4[r][2] * f4[b][2] + w4[r][3] * f4[b][3];
  }
#pragma unroll
  for (int r = 0; r < 4; ++r)
#pragma unroll
    for (int b = 0; b < 8; ++b) {
      float v = acc[r][b];
      v += __shfl_down(v, 32, 64);
      v += __shfl_down(v, 16, 64);
      v += __shfl_down(v, 8, 64);
      acc[r][b] = v;
    }
  if (lane < 8) {
#pragma unroll
    for (int r = 0; r < 4; ++r)
#pragma unroll
      for (int b = 0; b < 8; ++b) red[W][lane][r * 8 + b] = acc[r][b];
  }
  __syncthreads();
  if (t < 32) {
    float sum = 0.f;
#pragma unroll
    for (int w = 0; w < 4; ++w)
#pragma unroll
      for (int l = 0; l < 8; ++l) sum += red[w][l][t];
    int r = t >> 3, b = t & 7;
    part6[(size_t)kc * 8192 + (r0 + r) * 8 + b] = sum;
  }
}

// ---------------------------------------------------------------------------
// Kernel 6: reduce fc6 partials + bias + relu -> h[b][r]
// ---------------------------------------------------------------------------
__global__ __launch_bounds__(256, 1) void k_h(
    const float* __restrict__ part6, const float* __restrict__ b6,
    float* __restrict__ h) {
  int idx = blockIdx.x * 256 + threadIdx.x;   // 8192
  int r = idx >> 3, b = idx & 7;
  float s = b6[r];
#pragma unroll
  for (int kc = 0; kc < 8; ++kc) s += part6[(size_t)kc * 8192 + r * 8 + b];
  h[b * 1024 + r] = fmaxf(s, 0.f);
}

// ---------------------------------------------------------------------------
// Kernel 7: fc7 wave-per-row + bias + relu -> out[b][r]
// ---------------------------------------------------------------------------
__global__ __launch_bounds__(256, 1) void k_fc7(
    const float* __restrict__ h, const float* __restrict__ w7,
    const float* __restrict__ b7, float* __restrict__ out) {
  int bid = blockIdx.x;                        // 256
  int t = threadIdx.x, W = t >> 6, lane = t & 63;
  int r = bid * 4 + W;
  float acc[8] = {0, 0, 0, 0, 0, 0, 0, 0};
#pragma unroll
  for (int step = 0; step < 4; ++step) {
    int k = step * 256 + lane * 4;
    f32x4 w4 = *reinterpret_cast<const f32x4*>(w7 + (size_t)r * 1024 + k);
#pragma unroll
    for (int b = 0; b < 8; ++b) {
      f32x4 h4 = *reinterpret_cast<const f32x4*>(h + b * 1024 + k);
      acc[b] += w4[0] * h4[0] + w4[1] * h4[1] + w4[2] * h4[2] + w4[3] * h4[3];
    }
  }
#pragma unroll
  for (int b = 0; b < 8; ++b) {
    float v = acc[b];
#pragma unroll
    for (int off = 32; off > 0; off >>= 1) v += __shfl_down(v, off, 64);
    acc[b] = v;
  }
  if (lane == 0) {
#pragma unroll
    for (int b = 0; b < 8; ++b) out[b * 1024 + r] = fmaxf(acc[b] + b7[r], 0.f);
  }
}

// ---------------------------------------------------------------------------
extern "C" void kernel_launch(void* const* d_in, const int* in_sizes, int n_in,
                              void* d_out, int out_size, void* d_ws, size_t ws_size,
                              hipStream_t stream) {
  const float* x  = (const float*)d_in[0];
  const float* cw = (const float*)d_in[1];
  const float* cb = (const float*)d_in[2];
  const float* w6 = (const float*)d_in[3];
  const float* b6 = (const float*)d_in[4];
  const float* w7 = (const float*)d_in[5];
  const float* b7 = (const float*)d_in[6];
  float* out   = (float*)d_out;            // (8,1024) = 8192
  float* xpool = out + 8192;               // (8,512,64) = 262144

  char* ws = (char*)d_ws;
  unsigned short* xT  = (unsigned short*)(ws);                 //  6,422,528 B
  unsigned short* wpk = (unsigned short*)(ws + 6422528);       //    589,824 B
  float* am_part      = (float*)(ws + 7012352);                //  6,422,528 B
  float* pmax         = (float*)(ws + 13434880);               // 14,680,064 B
  float* part6        = (float*)(ws + 28114944);               //    262,144 B
  float* hbuf         = (float*)(ws + 28377088);               //     32,768 B

  hipLaunchKernelGGL(k_xpose,   dim3(968),  dim3(256), 0, stream, x, cw, xT, wpk);
  hipLaunchKernelGGL(k_conv,    dim3(448),  dim3(128), 0, stream, xT, wpk, cb, am_part);
  hipLaunchKernelGGL(k_pool,    dim3(224),  dim3(256), 0, stream, xT, am_part, pmax);
  hipLaunchKernelGGL(k_combine, dim3(256),  dim3(256), 0, stream, pmax, xpool);
  hipLaunchKernelGGL(k_fc6,     dim3(2048), dim3(256), 0, stream, xpool, w6, part6);
  hipLaunchKernelGGL(k_h,       dim3(32),   dim3(256), 0, stream, part6, b6, hbuf);
  hipLaunchKernelGGL(k_fc7,     dim3(256),  dim3(256), 0, stream, hbuf, w7, b7, out);
}